// Round 12
// baseline (166.114 us; speedup 1.0000x reference)
//
#include <hip/hip_runtime.h>

// PROBE ROUND: byte-identical r11 structure, but feats runs its body 3x
// (recompute + rewrite identical values). Purpose: split the F/V ledger
// (F = (total3 - 88.1)/2) and force the feats dispatch (~3F >= 130 us) into
// rocprof's top-5 so we finally see its VGPR/VALUBusy/hbm/occupancy counters.
// Output is bit-identical to round 11 (passes re-store the same values).
// B=256, T=256, H=768, L=13, START=11.
// Outputs (float32): [0..255] max_p/T; [256..65791] path.

#define NEGV (-10000.0f)

// v += dpp_move(v) entirely on the VALU pipe. ctrl/rmask are literals.
#define DPP_ADD(v, ctrl, rmask)                                               \
  v += __int_as_float(__builtin_amdgcn_update_dpp(                            \
      0, __float_as_int(v), (ctrl), (rmask), 0xF, true));

// full 64-lane sum -> lane 63 holds the total
#define DPP_REDUCE64(v)                                                       \
  DPP_ADD(v, 0x111, 0xF)  /* row_shr:1  */                                    \
  DPP_ADD(v, 0x112, 0xF)  /* row_shr:2  */                                    \
  DPP_ADD(v, 0x114, 0xF)  /* row_shr:4  */                                    \
  DPP_ADD(v, 0x118, 0xF)  /* row_shr:8  */                                    \
  DPP_ADD(v, 0x142, 0xA)  /* row_bcast:15 -> rows 1,3 */                      \
  DPP_ADD(v, 0x143, 0xC)  /* row_bcast:31 -> rows 2,3 */

// ---------------------------------------------------------------- kernel 1 --
__global__ __launch_bounds__(256, 2) void feats_kernel(
    const float* __restrict__ X,      // [65536, 768]
    const float* __restrict__ W,      // [13, 768]
    const float* __restrict__ bias,   // [13]
    float* __restrict__ featsT)       // [13][65536]
{
  const int tid = threadIdx.x;
  const int w = tid >> 6, l = tid & 63;
  const long row0 = (long)blockIdx.x * 128 + w * 32;

  // W -> VGPRs, k-slice layout (one-time; L2-cached across waves)
  float wreg[13][12];
  #pragma unroll
  for (int col = 0; col < 13; ++col) {
    #pragma unroll
    for (int j = 0; j < 3; ++j) {
      float4 v = *reinterpret_cast<const float4*>(W + col * 768 + 256 * j + 4 * l);
      wreg[col][4 * j + 0] = v.x; wreg[col][4 * j + 1] = v.y;
      wreg[col][4 * j + 2] = v.z; wreg[col][4 * j + 3] = v.w;
    }
  }
  float bs[13];
  #pragma unroll
  for (int c = 0; c < 13; ++c) bs[c] = bias[c];

  const float* xp = X + row0 * 768 + 4 * l;

  // ===== PROBE: run the r11 body 3x; passes write identical values =====
  #pragma unroll 1
  for (int rep = 0; rep < 3; ++rep) {
    // 4-deep ring prefetch: rows 0..3
    float4 buf[4][3];
    #pragma unroll
    for (int i = 0; i < 4; ++i) {
      buf[i][0] = *reinterpret_cast<const float4*>(xp + i * 768);
      buf[i][1] = *reinterpret_cast<const float4*>(xp + i * 768 + 256);
      buf[i][2] = *reinterpret_cast<const float4*>(xp + i * 768 + 512);
    }

    #pragma unroll 4
    for (int r = 0; r < 32; ++r) {
      const int s = r & 3;              // static after unroll
      const float x[12] = {buf[s][0].x, buf[s][0].y, buf[s][0].z, buf[s][0].w,
                           buf[s][1].x, buf[s][1].y, buf[s][1].z, buf[s][1].w,
                           buf[s][2].x, buf[s][2].y, buf[s][2].z, buf[s][2].w};

      // UNCONDITIONAL refill of this slot (tail clamps to row 31)
      {
        const int pr = (r + 4 < 32) ? (r + 4) : 31;
        const float* xn = xp + pr * 768;
        buf[s][0] = *reinterpret_cast<const float4*>(xn);
        buf[s][1] = *reinterpret_cast<const float4*>(xn + 256);
        buf[s][2] = *reinterpret_cast<const float4*>(xn + 512);
      }

      float acc[13];
      #pragma unroll
      for (int c = 0; c < 13; ++c) acc[c] = 0.0f;
      #pragma unroll
      for (int col = 0; col < 13; ++col)
        #pragma unroll
        for (int k = 0; k < 12; ++k)
          acc[col] = fmaf(x[k], wreg[col][k], acc[col]);

      // 13 independent DPP tree-sums (VALU pipe only)
      #pragma unroll
      for (int c = 0; c < 13; ++c) {
        DPP_REDUCE64(acc[c])
      }

      // all 13 totals live in lane 63's acc[c] registers
      if (l == 63) {
        #pragma unroll
        for (int c = 0; c < 13; ++c)
          featsT[(long)c * 65536 + row0 + r] = acc[c] + bs[c];
      }
    }
  }
}

// ---------------------------------------------------------------- kernel 2 --
// (byte-identical to round 4/9/11's passing viterbi kernel)
__global__ __launch_bounds__(256) void viterbi_kernel(
    const float* __restrict__ featsT,  // [13][65536]
    const float* __restrict__ trans,   // [13,13]
    float* __restrict__ out)           // [256 + 65536]
{
  __shared__ float fsT[13 * 260];          // feats transposed [to][t] (pad 260)
  __shared__ float lds_ld[256 * 16];       // ld_t[to], t = 0..255
  __shared__ float trL[176];               // trans (169 used)
  __shared__ unsigned char psi[256 * 16];  // psi[t][to]
  __shared__ unsigned char Mm[256];        // [16 chunks][16]
  __shared__ unsigned char bnd[16];
  __shared__ unsigned char path[256];

  const int tid = threadIdx.x;
  const int w = tid >> 6, lane = tid & 63;
  const int b = blockIdx.x;

  #pragma unroll
  for (int i = 0; i < 13; ++i)
    fsT[i * 260 + tid] = featsT[(long)i * 65536 + b * 256 + tid];
  if (tid < 169) trL[tid] = trans[tid];
  __syncthreads();

  // ---- phase 1: serial forward (values only), wave 0, lower half-wave ----
  if (w == 0 && lane < 16) {
    float tr[13];
    #pragma unroll
    for (int f = 0; f < 13; ++f)
      tr[f] = (lane < 13) ? trans[lane * 13 + f] : -1.0e30f;

    const int toc = (lane < 13) ? lane : 0;
    const float* frow = &fsT[toc * 260];

    float ld = (lane == 11) ? 0.0f : NEGV;  // START = 11
    if (lane < 13) lds_ld[lane] = ld;       // t = 0

    float4 F[4], Fn[4];
    #pragma unroll
    for (int q = 0; q < 4; ++q)
      F[q] = *reinterpret_cast<const float4*>(frow + 4 * q);

    #pragma unroll 1
    for (int g = 0; g < 16; ++g) {
      if (g < 15) {
        #pragma unroll
        for (int q = 0; q < 4; ++q)
          Fn[q] = *reinterpret_cast<const float4*>(frow + (g + 1) * 16 + 4 * q);
      }
      const int kLo = (g == 0) ? 1 : 0;     // skip t = 0
      #pragma unroll
      for (int k = 0; k < 16; ++k) {
        if (k < kLo) continue;
        const int t = g * 16 + k;
        float c[13];
        #pragma unroll
        for (int f = 0; f < 13; ++f) {
          float lf = __uint_as_float(
              __builtin_amdgcn_readlane(__float_as_uint(ld), f));
          c[f] = tr[f] + lf;
        }
        float p0 = fmaxf(fmaxf(c[0], c[1]), c[2]);
        float p1 = fmaxf(fmaxf(c[3], c[4]), c[5]);
        float p2 = fmaxf(fmaxf(c[6], c[7]), c[8]);
        float p3 = fmaxf(fmaxf(c[9], c[10]), c[11]);
        float m  = fmaxf(fmaxf(fmaxf(p0, p1), p2), fmaxf(p3, c[12]));

        const float4 fq = F[k >> 2];
        const float ft = ((k & 3) == 0) ? fq.x : ((k & 3) == 1) ? fq.y
                        : ((k & 3) == 2) ? fq.z : fq.w;
        ld = m + ft;
        if (lane < 13) lds_ld[t * 16 + lane] = ld;
      }
      #pragma unroll
      for (int q = 0; q < 4; ++q) F[q] = Fn[q];
    }
  }
  __syncthreads();

  // ---- phase 2: psi in parallel over t ----
  {
    const int to = tid & 15, dtt = tid >> 4;
    if (to < 13) {
      float trr[13];
      #pragma unroll
      for (int f = 0; f < 13; ++f) trr[f] = trL[to * 13 + f];
      for (int t = (dtt == 0 ? 16 : dtt); t < 256; t += 16) {
        const float* lp = &lds_ld[(t - 1) * 16];
        float4 l0 = *reinterpret_cast<const float4*>(lp);
        float4 l1 = *reinterpret_cast<const float4*>(lp + 4);
        float4 l2 = *reinterpret_cast<const float4*>(lp + 8);
        float4 l3 = *reinterpret_cast<const float4*>(lp + 12);
        float c[13] = {trr[0] + l0.x,  trr[1] + l0.y,  trr[2] + l0.z,
                       trr[3] + l0.w,  trr[4] + l1.x,  trr[5] + l1.y,
                       trr[6] + l1.z,  trr[7] + l1.w,  trr[8] + l2.x,
                       trr[9] + l2.y,  trr[10] + l2.z, trr[11] + l2.w,
                       trr[12] + l3.x};
        float best = c[0]; int bf = 0;
        #pragma unroll
        for (int f = 1; f < 13; ++f) {
          bool gt = c[f] > best;              // strict >: first index wins
          best = gt ? c[f] : best;
          bf   = gt ? f : bf;
        }
        psi[t * 16 + to] = (unsigned char)bf;
      }
    }
  }
  __syncthreads();

  // ---- phase 3: ancestor maps ----
  {
    const int sS = tid & 15, g = tid >> 4;
    if (sS < 13) {
      int cur = sS;
      const int tLo = (g == 0) ? 1 : g * 16;
      for (int t = g * 16 + 15; t >= tLo; --t)
        cur = psi[t * 16 + cur];
      Mm[g * 16 + sS] = (unsigned char)cur;
    }
  }
  __syncthreads();

  // ---- phase 4: softmax output + boundary chase ----
  if (tid == 0) {
    const float* lf = &lds_ld[255 * 16];
    float m = lf[0]; int last = 0;
    #pragma unroll
    for (int i = 1; i < 13; ++i)
      if (lf[i] > m) { m = lf[i]; last = i; }   // strict >: first index
    float ssum = 0.0f;
    #pragma unroll
    for (int i = 0; i < 13; ++i) ssum += expf(lf[i] - m);
    out[b] = 1.0f / (256.0f * ssum);            // max(softmax)/T

    int cur = last;
    bnd[15] = (unsigned char)cur;
    #pragma unroll
    for (int cc = 15; cc >= 1; --cc) {
      cur = Mm[cc * 16 + cur];
      bnd[cc - 1] = (unsigned char)cur;
    }
  }
  __syncthreads();

  // ---- phase 5: interior chases ----
  if (tid < 16) {
    int cur = bnd[tid];
    const int tHi = tid * 16 + 15;
    path[tHi] = (unsigned char)cur;
    const int tLo = (tid == 0) ? 1 : tid * 16;
    for (int t = tHi; t >= tLo; --t) {
      cur = psi[t * 16 + cur];
      path[t - 1] = (unsigned char)cur;
    }
  }
  __syncthreads();

  out[256 + (long)b * 256 + tid] = (float)path[tid];
}

// ------------------------------------------------------------------ launch --
extern "C" void kernel_launch(void* const* d_in, const int* in_sizes, int n_in,
                              void* d_out, int out_size, void* d_ws, size_t ws_size,
                              hipStream_t stream) {
  const float* X     = (const float*)d_in[0];
  const float* W     = (const float*)d_in[1];
  const float* bias  = (const float*)d_in[2];
  const float* trans = (const float*)d_in[3];
  float* out    = (float*)d_out;
  float* featsT = (float*)d_ws;   // 13*65536 floats = 3.4 MB

  feats_kernel<<<512, 256, 0, stream>>>(X, W, bias, featsT);
  viterbi_kernel<<<256, 256, 0, stream>>>(featsT, trans, out);
}

// Round 13
// 88.050 us; speedup vs baseline: 1.8866x; 1.8866x over previous
//
#include <hip/hip_runtime.h>

// BERT-CRF NER, two kernels.
//  K1 feats (v7): identical structure to r11, two changes:
//   (a) __launch_bounds__(256, 1): VGPR cap 512 so the allocator keeps
//       wreg[13][12] (156 regs) RESIDENT — r5..r12 all show VGPR<=132, i.e.
//       W was spilled/reloaded every row (the real feats bottleneck).
//   (b) loop body reordered FMA -> DPP -> store -> refill, so buf[s] is
//       consumed before overwrite (no x[12] snapshot, -12 regs, -12 movs).
//  K2 viterbi: byte-identical to round 4/9/11's passing kernel.
// B=256, T=256, H=768, L=13, START=11.
// Outputs (float32): [0..255] max_p/T; [256..65791] path.

#define NEGV (-10000.0f)

// v += dpp_move(v) entirely on the VALU pipe. ctrl/rmask are literals.
#define DPP_ADD(v, ctrl, rmask)                                               \
  v += __int_as_float(__builtin_amdgcn_update_dpp(                            \
      0, __float_as_int(v), (ctrl), (rmask), 0xF, true));

// full 64-lane sum -> lane 63 holds the total
#define DPP_REDUCE64(v)                                                       \
  DPP_ADD(v, 0x111, 0xF)  /* row_shr:1  */                                    \
  DPP_ADD(v, 0x112, 0xF)  /* row_shr:2  */                                    \
  DPP_ADD(v, 0x114, 0xF)  /* row_shr:4  */                                    \
  DPP_ADD(v, 0x118, 0xF)  /* row_shr:8  */                                    \
  DPP_ADD(v, 0x142, 0xA)  /* row_bcast:15 -> rows 1,3 */                      \
  DPP_ADD(v, 0x143, 0xC)  /* row_bcast:31 -> rows 2,3 */

// ---------------------------------------------------------------- kernel 1 --
// Wave = reduction unit; lane l owns k-slice {4l..4l+3, 256+4l.., 512+4l..}.
// Each wave computes 32 consecutive rows; block (4 waves) = 128 rows.
__global__ __launch_bounds__(256, 1) void feats_kernel(
    const float* __restrict__ X,      // [65536, 768]
    const float* __restrict__ W,      // [13, 768]
    const float* __restrict__ bias,   // [13]
    float* __restrict__ featsT)       // [13][65536]
{
  const int tid = threadIdx.x;
  const int w = tid >> 6, l = tid & 63;
  const long row0 = (long)blockIdx.x * 128 + w * 32;

  // W -> VGPRs, k-slice layout; MUST stay resident (launch_bounds(256,1))
  float wreg[13][12];
  #pragma unroll
  for (int col = 0; col < 13; ++col) {
    #pragma unroll
    for (int j = 0; j < 3; ++j) {
      float4 v = *reinterpret_cast<const float4*>(W + col * 768 + 256 * j + 4 * l);
      wreg[col][4 * j + 0] = v.x; wreg[col][4 * j + 1] = v.y;
      wreg[col][4 * j + 2] = v.z; wreg[col][4 * j + 3] = v.w;
    }
  }
  float bs[13];
  #pragma unroll
  for (int c = 0; c < 13; ++c) bs[c] = bias[c];   // uniform -> scalar loads

  const float* xp = X + row0 * 768 + 4 * l;

  // 4-deep ring prefetch: rows 0..3
  float4 buf[4][3];
  #pragma unroll
  for (int i = 0; i < 4; ++i) {
    buf[i][0] = *reinterpret_cast<const float4*>(xp + i * 768);
    buf[i][1] = *reinterpret_cast<const float4*>(xp + i * 768 + 256);
    buf[i][2] = *reinterpret_cast<const float4*>(xp + i * 768 + 512);
  }

  #pragma unroll 4
  for (int r = 0; r < 32; ++r) {
    const int s = r & 3;                // static after unroll
    const float4 b0 = buf[s][0], b1 = buf[s][1], b2 = buf[s][2];

    float acc[13];
    #pragma unroll
    for (int c = 0; c < 13; ++c) acc[c] = 0.0f;
    #pragma unroll
    for (int col = 0; col < 13; ++col) {
      acc[col] = fmaf(b0.x, wreg[col][0],  acc[col]);
      acc[col] = fmaf(b0.y, wreg[col][1],  acc[col]);
      acc[col] = fmaf(b0.z, wreg[col][2],  acc[col]);
      acc[col] = fmaf(b0.w, wreg[col][3],  acc[col]);
      acc[col] = fmaf(b1.x, wreg[col][4],  acc[col]);
      acc[col] = fmaf(b1.y, wreg[col][5],  acc[col]);
      acc[col] = fmaf(b1.z, wreg[col][6],  acc[col]);
      acc[col] = fmaf(b1.w, wreg[col][7],  acc[col]);
      acc[col] = fmaf(b2.x, wreg[col][8],  acc[col]);
      acc[col] = fmaf(b2.y, wreg[col][9],  acc[col]);
      acc[col] = fmaf(b2.z, wreg[col][10], acc[col]);
      acc[col] = fmaf(b2.w, wreg[col][11], acc[col]);
    }

    // 13 independent DPP tree-sums (VALU pipe only; chains interleave)
    #pragma unroll
    for (int c = 0; c < 13; ++c) {
      DPP_REDUCE64(acc[c])
    }

    // all 13 totals live in lane 63's acc[c] registers: store from lane 63
    if (l == 63) {
      #pragma unroll
      for (int c = 0; c < 13; ++c)
        featsT[(long)c * 65536 + row0 + r] = acc[c] + bs[c];
    }

    // UNCONDITIONAL refill of this slot AFTER use (tail clamps to row 31:
    // redundant, harmless, keeps vmcnt countable -> no full drains)
    {
      const int pr = (r + 4 < 32) ? (r + 4) : 31;   // scalar cselect
      const float* xn = xp + pr * 768;
      buf[s][0] = *reinterpret_cast<const float4*>(xn);
      buf[s][1] = *reinterpret_cast<const float4*>(xn + 256);
      buf[s][2] = *reinterpret_cast<const float4*>(xn + 512);
    }
  }
}

// ---------------------------------------------------------------- kernel 2 --
// (byte-identical to round 4/9/11's passing viterbi kernel)
__global__ __launch_bounds__(256) void viterbi_kernel(
    const float* __restrict__ featsT,  // [13][65536]
    const float* __restrict__ trans,   // [13,13]
    float* __restrict__ out)           // [256 + 65536]
{
  __shared__ float fsT[13 * 260];          // feats transposed [to][t] (pad 260)
  __shared__ float lds_ld[256 * 16];       // ld_t[to], t = 0..255
  __shared__ float trL[176];               // trans (169 used)
  __shared__ unsigned char psi[256 * 16];  // psi[t][to]
  __shared__ unsigned char Mm[256];        // [16 chunks][16]
  __shared__ unsigned char bnd[16];
  __shared__ unsigned char path[256];

  const int tid = threadIdx.x;
  const int w = tid >> 6, lane = tid & 63;
  const int b = blockIdx.x;

  #pragma unroll
  for (int i = 0; i < 13; ++i)
    fsT[i * 260 + tid] = featsT[(long)i * 65536 + b * 256 + tid];
  if (tid < 169) trL[tid] = trans[tid];
  __syncthreads();

  // ---- phase 1: serial forward (values only), wave 0, lower half-wave ----
  if (w == 0 && lane < 16) {
    float tr[13];
    #pragma unroll
    for (int f = 0; f < 13; ++f)
      tr[f] = (lane < 13) ? trans[lane * 13 + f] : -1.0e30f;

    const int toc = (lane < 13) ? lane : 0;
    const float* frow = &fsT[toc * 260];

    float ld = (lane == 11) ? 0.0f : NEGV;  // START = 11
    if (lane < 13) lds_ld[lane] = ld;       // t = 0

    float4 F[4], Fn[4];
    #pragma unroll
    for (int q = 0; q < 4; ++q)
      F[q] = *reinterpret_cast<const float4*>(frow + 4 * q);

    #pragma unroll 1
    for (int g = 0; g < 16; ++g) {
      if (g < 15) {
        #pragma unroll
        for (int q = 0; q < 4; ++q)
          Fn[q] = *reinterpret_cast<const float4*>(frow + (g + 1) * 16 + 4 * q);
      }
      const int kLo = (g == 0) ? 1 : 0;     // skip t = 0
      #pragma unroll
      for (int k = 0; k < 16; ++k) {
        if (k < kLo) continue;
        const int t = g * 16 + k;
        float c[13];
        #pragma unroll
        for (int f = 0; f < 13; ++f) {
          float lf = __uint_as_float(
              __builtin_amdgcn_readlane(__float_as_uint(ld), f));
          c[f] = tr[f] + lf;
        }
        float p0 = fmaxf(fmaxf(c[0], c[1]), c[2]);
        float p1 = fmaxf(fmaxf(c[3], c[4]), c[5]);
        float p2 = fmaxf(fmaxf(c[6], c[7]), c[8]);
        float p3 = fmaxf(fmaxf(c[9], c[10]), c[11]);
        float m  = fmaxf(fmaxf(fmaxf(p0, p1), p2), fmaxf(p3, c[12]));

        const float4 fq = F[k >> 2];
        const float ft = ((k & 3) == 0) ? fq.x : ((k & 3) == 1) ? fq.y
                        : ((k & 3) == 2) ? fq.z : fq.w;
        ld = m + ft;
        if (lane < 13) lds_ld[t * 16 + lane] = ld;
      }
      #pragma unroll
      for (int q = 0; q < 4; ++q) F[q] = Fn[q];
    }
  }
  __syncthreads();

  // ---- phase 2: psi in parallel over t ----
  {
    const int to = tid & 15, dtt = tid >> 4;
    if (to < 13) {
      float trr[13];
      #pragma unroll
      for (int f = 0; f < 13; ++f) trr[f] = trL[to * 13 + f];
      for (int t = (dtt == 0 ? 16 : dtt); t < 256; t += 16) {
        const float* lp = &lds_ld[(t - 1) * 16];
        float4 l0 = *reinterpret_cast<const float4*>(lp);
        float4 l1 = *reinterpret_cast<const float4*>(lp + 4);
        float4 l2 = *reinterpret_cast<const float4*>(lp + 8);
        float4 l3 = *reinterpret_cast<const float4*>(lp + 12);
        float c[13] = {trr[0] + l0.x,  trr[1] + l0.y,  trr[2] + l0.z,
                       trr[3] + l0.w,  trr[4] + l1.x,  trr[5] + l1.y,
                       trr[6] + l1.z,  trr[7] + l1.w,  trr[8] + l2.x,
                       trr[9] + l2.y,  trr[10] + l2.z, trr[11] + l2.w,
                       trr[12] + l3.x};
        float best = c[0]; int bf = 0;
        #pragma unroll
        for (int f = 1; f < 13; ++f) {
          bool gt = c[f] > best;              // strict >: first index wins
          best = gt ? c[f] : best;
          bf   = gt ? f : bf;
        }
        psi[t * 16 + to] = (unsigned char)bf;
      }
    }
  }
  __syncthreads();

  // ---- phase 3: ancestor maps ----
  {
    const int sS = tid & 15, g = tid >> 4;
    if (sS < 13) {
      int cur = sS;
      const int tLo = (g == 0) ? 1 : g * 16;
      for (int t = g * 16 + 15; t >= tLo; --t)
        cur = psi[t * 16 + cur];
      Mm[g * 16 + sS] = (unsigned char)cur;
    }
  }
  __syncthreads();

  // ---- phase 4: softmax output + boundary chase ----
  if (tid == 0) {
    const float* lf = &lds_ld[255 * 16];
    float m = lf[0]; int last = 0;
    #pragma unroll
    for (int i = 1; i < 13; ++i)
      if (lf[i] > m) { m = lf[i]; last = i; }   // strict >: first index
    float ssum = 0.0f;
    #pragma unroll
    for (int i = 0; i < 13; ++i) ssum += expf(lf[i] - m);
    out[b] = 1.0f / (256.0f * ssum);            // max(softmax)/T

    int cur = last;
    bnd[15] = (unsigned char)cur;
    #pragma unroll
    for (int cc = 15; cc >= 1; --cc) {
      cur = Mm[cc * 16 + cur];
      bnd[cc - 1] = (unsigned char)cur;
    }
  }
  __syncthreads();

  // ---- phase 5: interior chases ----
  if (tid < 16) {
    int cur = bnd[tid];
    const int tHi = tid * 16 + 15;
    path[tHi] = (unsigned char)cur;
    const int tLo = (tid == 0) ? 1 : tid * 16;
    for (int t = tHi; t >= tLo; --t) {
      cur = psi[t * 16 + cur];
      path[t - 1] = (unsigned char)cur;
    }
  }
  __syncthreads();

  out[256 + (long)b * 256 + tid] = (float)path[tid];
}

// ------------------------------------------------------------------ launch --
extern "C" void kernel_launch(void* const* d_in, const int* in_sizes, int n_in,
                              void* d_out, int out_size, void* d_ws, size_t ws_size,
                              hipStream_t stream) {
  const float* X     = (const float*)d_in[0];
  const float* W     = (const float*)d_in[1];
  const float* bias  = (const float*)d_in[2];
  const float* trans = (const float*)d_in[3];
  float* out    = (float*)d_out;
  float* featsT = (float*)d_ws;   // 13*65536 floats = 3.4 MB

  feats_kernel<<<512, 256, 0, stream>>>(X, W, bias, featsT);
  viterbi_kernel<<<256, 256, 0, stream>>>(featsT, trans, out);
}

// Round 14
// 86.948 us; speedup vs baseline: 1.9105x; 1.0127x over previous
//
#include <hip/hip_runtime.h>

// BERT-CRF NER, two kernels.
//  K1 feats (v8): r13 structure + __attribute__((amdgpu_waves_per_eu(2,2))):
//     pins the allocator's occupancy TARGET to 2 waves/SIMD (256-reg budget)
//     so wreg[13][12] (156 regs) stays in ARCH VGPRs — r12 counters proved
//     it was spilled at the default 128-reg target (VGPR_Count=128, 62%
//     VALUBusy from accvgpr/scratch reloads, ~10MB/rep scratch writes).
//  K2 viterbi: byte-identical to round 4/9/11/13's passing kernel.
// B=256, T=256, H=768, L=13, START=11.
// Outputs (float32): [0..255] max_p/T; [256..65791] path.

#define NEGV (-10000.0f)

// v += dpp_move(v) entirely on the VALU pipe. ctrl/rmask are literals.
#define DPP_ADD(v, ctrl, rmask)                                               \
  v += __int_as_float(__builtin_amdgcn_update_dpp(                            \
      0, __float_as_int(v), (ctrl), (rmask), 0xF, true));

// full 64-lane sum -> lane 63 holds the total
#define DPP_REDUCE64(v)                                                       \
  DPP_ADD(v, 0x111, 0xF)  /* row_shr:1  */                                    \
  DPP_ADD(v, 0x112, 0xF)  /* row_shr:2  */                                    \
  DPP_ADD(v, 0x114, 0xF)  /* row_shr:4  */                                    \
  DPP_ADD(v, 0x118, 0xF)  /* row_shr:8  */                                    \
  DPP_ADD(v, 0x142, 0xA)  /* row_bcast:15 -> rows 1,3 */                      \
  DPP_ADD(v, 0x143, 0xC)  /* row_bcast:31 -> rows 2,3 */

// ---------------------------------------------------------------- kernel 1 --
// Wave = reduction unit; lane l owns k-slice {4l..4l+3, 256+4l.., 512+4l..}.
// Each wave computes 32 consecutive rows; block (4 waves) = 128 rows.
__global__ __launch_bounds__(256)
__attribute__((amdgpu_waves_per_eu(2, 2)))
void feats_kernel(
    const float* __restrict__ X,      // [65536, 768]
    const float* __restrict__ W,      // [13, 768]
    const float* __restrict__ bias,   // [13]
    float* __restrict__ featsT)       // [13][65536]
{
  const int tid = threadIdx.x;
  const int w = tid >> 6, l = tid & 63;
  const long row0 = (long)blockIdx.x * 128 + w * 32;

  // W -> VGPRs, k-slice layout; resident under the 256-reg budget
  float wreg[13][12];
  #pragma unroll
  for (int col = 0; col < 13; ++col) {
    #pragma unroll
    for (int j = 0; j < 3; ++j) {
      float4 v = *reinterpret_cast<const float4*>(W + col * 768 + 256 * j + 4 * l);
      wreg[col][4 * j + 0] = v.x; wreg[col][4 * j + 1] = v.y;
      wreg[col][4 * j + 2] = v.z; wreg[col][4 * j + 3] = v.w;
    }
  }
  float bs[13];
  #pragma unroll
  for (int c = 0; c < 13; ++c) bs[c] = bias[c];   // uniform -> scalar regs

  const float* xp = X + row0 * 768 + 4 * l;

  // 4-deep ring prefetch: rows 0..3
  float4 buf[4][3];
  #pragma unroll
  for (int i = 0; i < 4; ++i) {
    buf[i][0] = *reinterpret_cast<const float4*>(xp + i * 768);
    buf[i][1] = *reinterpret_cast<const float4*>(xp + i * 768 + 256);
    buf[i][2] = *reinterpret_cast<const float4*>(xp + i * 768 + 512);
  }

  #pragma unroll 4
  for (int r = 0; r < 32; ++r) {
    const int s = r & 3;                // static after unroll
    const float4 b0 = buf[s][0], b1 = buf[s][1], b2 = buf[s][2];

    float acc[13];
    #pragma unroll
    for (int c = 0; c < 13; ++c) acc[c] = 0.0f;
    #pragma unroll
    for (int col = 0; col < 13; ++col) {
      acc[col] = fmaf(b0.x, wreg[col][0],  acc[col]);
      acc[col] = fmaf(b0.y, wreg[col][1],  acc[col]);
      acc[col] = fmaf(b0.z, wreg[col][2],  acc[col]);
      acc[col] = fmaf(b0.w, wreg[col][3],  acc[col]);
      acc[col] = fmaf(b1.x, wreg[col][4],  acc[col]);
      acc[col] = fmaf(b1.y, wreg[col][5],  acc[col]);
      acc[col] = fmaf(b1.z, wreg[col][6],  acc[col]);
      acc[col] = fmaf(b1.w, wreg[col][7],  acc[col]);
      acc[col] = fmaf(b2.x, wreg[col][8],  acc[col]);
      acc[col] = fmaf(b2.y, wreg[col][9],  acc[col]);
      acc[col] = fmaf(b2.z, wreg[col][10], acc[col]);
      acc[col] = fmaf(b2.w, wreg[col][11], acc[col]);
    }

    // 13 independent DPP tree-sums (VALU pipe only; chains interleave)
    #pragma unroll
    for (int c = 0; c < 13; ++c) {
      DPP_REDUCE64(acc[c])
    }

    // all 13 totals live in lane 63's acc[c] registers: store from lane 63
    if (l == 63) {
      #pragma unroll
      for (int c = 0; c < 13; ++c)
        featsT[(long)c * 65536 + row0 + r] = acc[c] + bs[c];
    }

    // UNCONDITIONAL refill of this slot AFTER use (tail clamps to row 31:
    // redundant, harmless, keeps vmcnt countable -> no full drains)
    {
      const int pr = (r + 4 < 32) ? (r + 4) : 31;   // scalar cselect
      const float* xn = xp + pr * 768;
      buf[s][0] = *reinterpret_cast<const float4*>(xn);
      buf[s][1] = *reinterpret_cast<const float4*>(xn + 256);
      buf[s][2] = *reinterpret_cast<const float4*>(xn + 512);
    }
  }
}

// ---------------------------------------------------------------- kernel 2 --
// (byte-identical to round 4/9/11/13's passing viterbi kernel)
__global__ __launch_bounds__(256) void viterbi_kernel(
    const float* __restrict__ featsT,  // [13][65536]
    const float* __restrict__ trans,   // [13,13]
    float* __restrict__ out)           // [256 + 65536]
{
  __shared__ float fsT[13 * 260];          // feats transposed [to][t] (pad 260)
  __shared__ float lds_ld[256 * 16];       // ld_t[to], t = 0..255
  __shared__ float trL[176];               // trans (169 used)
  __shared__ unsigned char psi[256 * 16];  // psi[t][to]
  __shared__ unsigned char Mm[256];        // [16 chunks][16]
  __shared__ unsigned char bnd[16];
  __shared__ unsigned char path[256];

  const int tid = threadIdx.x;
  const int w = tid >> 6, lane = tid & 63;
  const int b = blockIdx.x;

  #pragma unroll
  for (int i = 0; i < 13; ++i)
    fsT[i * 260 + tid] = featsT[(long)i * 65536 + b * 256 + tid];
  if (tid < 169) trL[tid] = trans[tid];
  __syncthreads();

  // ---- phase 1: serial forward (values only), wave 0, lower half-wave ----
  if (w == 0 && lane < 16) {
    float tr[13];
    #pragma unroll
    for (int f = 0; f < 13; ++f)
      tr[f] = (lane < 13) ? trans[lane * 13 + f] : -1.0e30f;

    const int toc = (lane < 13) ? lane : 0;
    const float* frow = &fsT[toc * 260];

    float ld = (lane == 11) ? 0.0f : NEGV;  // START = 11
    if (lane < 13) lds_ld[lane] = ld;       // t = 0

    float4 F[4], Fn[4];
    #pragma unroll
    for (int q = 0; q < 4; ++q)
      F[q] = *reinterpret_cast<const float4*>(frow + 4 * q);

    #pragma unroll 1
    for (int g = 0; g < 16; ++g) {
      if (g < 15) {
        #pragma unroll
        for (int q = 0; q < 4; ++q)
          Fn[q] = *reinterpret_cast<const float4*>(frow + (g + 1) * 16 + 4 * q);
      }
      const int kLo = (g == 0) ? 1 : 0;     // skip t = 0
      #pragma unroll
      for (int k = 0; k < 16; ++k) {
        if (k < kLo) continue;
        const int t = g * 16 + k;
        float c[13];
        #pragma unroll
        for (int f = 0; f < 13; ++f) {
          float lf = __uint_as_float(
              __builtin_amdgcn_readlane(__float_as_uint(ld), f));
          c[f] = tr[f] + lf;
        }
        float p0 = fmaxf(fmaxf(c[0], c[1]), c[2]);
        float p1 = fmaxf(fmaxf(c[3], c[4]), c[5]);
        float p2 = fmaxf(fmaxf(c[6], c[7]), c[8]);
        float p3 = fmaxf(fmaxf(c[9], c[10]), c[11]);
        float m  = fmaxf(fmaxf(fmaxf(p0, p1), p2), fmaxf(p3, c[12]));

        const float4 fq = F[k >> 2];
        const float ft = ((k & 3) == 0) ? fq.x : ((k & 3) == 1) ? fq.y
                        : ((k & 3) == 2) ? fq.z : fq.w;
        ld = m + ft;
        if (lane < 13) lds_ld[t * 16 + lane] = ld;
      }
      #pragma unroll
      for (int q = 0; q < 4; ++q) F[q] = Fn[q];
    }
  }
  __syncthreads();

  // ---- phase 2: psi in parallel over t ----
  {
    const int to = tid & 15, dtt = tid >> 4;
    if (to < 13) {
      float trr[13];
      #pragma unroll
      for (int f = 0; f < 13; ++f) trr[f] = trL[to * 13 + f];
      for (int t = (dtt == 0 ? 16 : dtt); t < 256; t += 16) {
        const float* lp = &lds_ld[(t - 1) * 16];
        float4 l0 = *reinterpret_cast<const float4*>(lp);
        float4 l1 = *reinterpret_cast<const float4*>(lp + 4);
        float4 l2 = *reinterpret_cast<const float4*>(lp + 8);
        float4 l3 = *reinterpret_cast<const float4*>(lp + 12);
        float c[13] = {trr[0] + l0.x,  trr[1] + l0.y,  trr[2] + l0.z,
                       trr[3] + l0.w,  trr[4] + l1.x,  trr[5] + l1.y,
                       trr[6] + l1.z,  trr[7] + l1.w,  trr[8] + l2.x,
                       trr[9] + l2.y,  trr[10] + l2.z, trr[11] + l2.w,
                       trr[12] + l3.x};
        float best = c[0]; int bf = 0;
        #pragma unroll
        for (int f = 1; f < 13; ++f) {
          bool gt = c[f] > best;              // strict >: first index wins
          best = gt ? c[f] : best;
          bf   = gt ? f : bf;
        }
        psi[t * 16 + to] = (unsigned char)bf;
      }
    }
  }
  __syncthreads();

  // ---- phase 3: ancestor maps ----
  {
    const int sS = tid & 15, g = tid >> 4;
    if (sS < 13) {
      int cur = sS;
      const int tLo = (g == 0) ? 1 : g * 16;
      for (int t = g * 16 + 15; t >= tLo; --t)
        cur = psi[t * 16 + cur];
      Mm[g * 16 + sS] = (unsigned char)cur;
    }
  }
  __syncthreads();

  // ---- phase 4: softmax output + boundary chase ----
  if (tid == 0) {
    const float* lf = &lds_ld[255 * 16];
    float m = lf[0]; int last = 0;
    #pragma unroll
    for (int i = 1; i < 13; ++i)
      if (lf[i] > m) { m = lf[i]; last = i; }   // strict >: first index
    float ssum = 0.0f;
    #pragma unroll
    for (int i = 0; i < 13; ++i) ssum += expf(lf[i] - m);
    out[b] = 1.0f / (256.0f * ssum);            // max(softmax)/T

    int cur = last;
    bnd[15] = (unsigned char)cur;
    #pragma unroll
    for (int cc = 15; cc >= 1; --cc) {
      cur = Mm[cc * 16 + cur];
      bnd[cc - 1] = (unsigned char)cur;
    }
  }
  __syncthreads();

  // ---- phase 5: interior chases ----
  if (tid < 16) {
    int cur = bnd[tid];
    const int tHi = tid * 16 + 15;
    path[tHi] = (unsigned char)cur;
    const int tLo = (tid == 0) ? 1 : tid * 16;
    for (int t = tHi; t >= tLo; --t) {
      cur = psi[t * 16 + cur];
      path[t - 1] = (unsigned char)cur;
    }
  }
  __syncthreads();

  out[256 + (long)b * 256 + tid] = (float)path[tid];
}

// ------------------------------------------------------------------ launch --
extern "C" void kernel_launch(void* const* d_in, const int* in_sizes, int n_in,
                              void* d_out, int out_size, void* d_ws, size_t ws_size,
                              hipStream_t stream) {
  const float* X     = (const float*)d_in[0];
  const float* W     = (const float*)d_in[1];
  const float* bias  = (const float*)d_in[2];
  const float* trans = (const float*)d_in[3];
  float* out    = (float*)d_out;
  float* featsT = (float*)d_ws;   // 13*65536 floats = 3.4 MB

  feats_kernel<<<512, 256, 0, stream>>>(X, W, bias, featsT);
  viterbi_kernel<<<256, 256, 0, stream>>>(featsT, trans, out);
}